// Round 14
// baseline (36.355 us; speedup 1.0000x reference)
//
#include <hip/hip_runtime.h>
#include <hip/hip_bf16.h>
#include <math.h>

// ---------------------------------------------------------------------------
// RnCLoss: loss = -1/(n(n-1)) * sum_{i, k!=i} [ logit(i,k) - log denom(i,k) ]
//   logit(i,j) = 0.5*sqrt(max(2 - 2*G_ij*rsqrt(G_ii*G_jj), 0)), G = F F^T
//   denom(i,k) = sum_{j!=i, |l_i-l_j| >= |l_i-l_k|} exp(logit(i,j))
//
// Kernel 1 (258 blocks): R13's proven single-shot-K bf16-MFMA GEMM (blocks
//   0..255) + brute-force stable label ranks (blocks 256,257) + counter init.
// Kernel 2 (512 blocks): sorted-domain per-row loss (R13 body) + SPIN-FREE
//   TWO-TIER LAST-ARRIVER FINALIZE (replaces the k_final dispatch):
//     tier 1: 32 group counters on separate cachelines (16-deep RMW each,
//             parallel across lines; R12 calibration ~20ns/RMW -> ~0.3us);
//             group's last arriver tree-reduces its 16 row_sums -> gsum[g].
//     tier 2: one final counter (32-deep); overall last arriver tree-reduces
//             the 32 gsum -> out[0].
//   No spinning -> no co-residency/deadlock concerns; fixed reduction trees
//   -> deterministic regardless of arrival order.
// ---------------------------------------------------------------------------

typedef __attribute__((ext_vector_type(8))) short          short8;
typedef __attribute__((ext_vector_type(4))) unsigned short ushort4v;
typedef __attribute__((ext_vector_type(4))) float          f32x4;

static __device__ __forceinline__ unsigned short bf16_bits(float f) {
    __hip_bfloat16 h = __float2bfloat16(f);  // RNE
    return *reinterpret_cast<unsigned short*>(&h);
}

// Kernel 1 -------------------------------------------------------------------
// Requires d == 512 (fixed by the problem's setup_inputs).
__global__ __launch_bounds__(256) void k_gemm_rank(const float* __restrict__ F,
                                                   const float* __restrict__ labels,
                                                   float* __restrict__ G,
                                                   float* __restrict__ diag,
                                                   float* __restrict__ mlab,
                                                   int* __restrict__ perm,
                                                   unsigned* __restrict__ ctrs,
                                                   int n, int d) {
    // 64 KB LDS pool: A image [32][512] + B image [32][512] bf16 (XOR-swizzled)
    __shared__ unsigned short Asm[32][512];
    __shared__ unsigned short Bsm[32][512];

    const int b = blockIdx.x;
    const int t = threadIdx.x;

    // zero finalize counters: 33 cacheline-separated u32 (stride 64 = 256 B)
    if (b == 0 && t < 33) ctrs[t * 64] = 0u;

    if (b >= 256) {
        // ---- brute-force stable ranks (blocks 256,257); reuse LDS pool ----
        float* ls = (float*)&Asm[0][0];
        for (int x = t; x < n; x += 256) ls[x] = labels[x];
        __syncthreads();
        const int j = (b - 256) * 256 + t;
        const float lj = ls[j];
        int cnt = 0;
        #pragma unroll 8
        for (int x = 0; x < 512; ++x) {
            float lx = ls[x];                   // wave-uniform -> broadcast
            cnt += (lx < lj) || (lx == lj && x < j);
        }
        mlab[cnt] = lj;                          // ranks unique -> no race
        perm[cnt] = j;
        return;
    }

    // ---- GEMM: 32x32 tile, 4 waves (one 16x16 frag each), BK = 512 ----
    const int l  = t & 63;
    const int w  = t >> 6;
    const int wr = (w >> 1) << 4;   // frag row base: 0/16
    const int wc = (w & 1) << 4;    // frag col base: 0/16

    const int i0 = (b >> 4) << 5;
    const int j0 = (b & 15) << 5;

    const int fr = l & 15;          // frag row within 16x16
    const int fk = (l >> 4) << 3;   // frag k base: 0,8,16,24

    // single-shot staging: 16 passes x (2 coalesced float4 loads)
    #pragma unroll
    for (int p = 0; p < 16; ++p) {
        const int idx = p * 1024 + t * 4;
        const int row = idx >> 9;
        const int col = idx & 511;
        float4 av = *(const float4*)&F[(size_t)(i0 + row) * 512 + col];
        float4 bv = *(const float4*)&F[(size_t)(j0 + row) * 512 + col];
        ushort4v ua, ub;
        ua[0] = bf16_bits(av.x); ua[1] = bf16_bits(av.y);
        ua[2] = bf16_bits(av.z); ua[3] = bf16_bits(av.w);
        ub[0] = bf16_bits(bv.x); ub[1] = bf16_bits(bv.y);
        ub[2] = bf16_bits(bv.z); ub[3] = bf16_bits(bv.w);
        const int cu = col ^ ((row & 7) << 3);   // 16B-granule XOR swizzle
        *(ushort4v*)&Asm[row][cu] = ua;
        *(ushort4v*)&Bsm[row][cu] = ub;
    }
    __syncthreads();   // the only barrier

    // 16 K-steps: 2 x ds_read_b128 + 1 MFMA each, no further syncs
    const int rA = wr + fr;
    const int rB = wc + fr;
    const int sxA = (rA & 7) << 3;
    const int sxB = (rB & 7) << 3;
    f32x4 acc = {};
    #pragma unroll
    for (int ks = 0; ks < 16; ++ks) {
        const int colk = ks * 32 + fk;
        short8 af = *(const short8*)&Asm[rA][colk ^ sxA];
        short8 bf = *(const short8*)&Bsm[rB][colk ^ sxB];
        acc = __builtin_amdgcn_mfma_f32_16x16x32_bf16(af, bf, acc, 0, 0, 0);
    }

    // epilogue: C/D mapping col=lane&15, row=(lane>>4)*4+r (G symmetric)
    const int orow = (l >> 4) << 2;
    #pragma unroll
    for (int r = 0; r < 4; ++r) {
        int gi = i0 + wr + orow + r;
        int gj = j0 + wc + fr;
        float v = acc[r];
        G[(size_t)gi * n + gj] = v;
        if (gi == gj) diag[gi] = v;
    }
}

// Kernel 2: sorted-domain per-row loss + two-tier last-arriver finalize ------
__global__ __launch_bounds__(256) void k_loss(const float* __restrict__ labels,
                                              const float* __restrict__ G,
                                              const float* __restrict__ diag,
                                              const float* __restrict__ mlab,
                                              const int* __restrict__ perm,
                                              float* __restrict__ row_sums,
                                              float* __restrict__ gsum,
                                              unsigned* __restrict__ ctrs,
                                              float* __restrict__ out,
                                              int n) {
    const int i    = blockIdx.x;
    const int t    = threadIdx.x;
    const int lane = t & 63;
    const int w    = t >> 6;

    __shared__ float m_s[512];      // sorted labels
    __shared__ int   pm_s[512];     // sorted pos -> natural index
    __shared__ float dg_s[512];     // diag, natural order
    __shared__ float g_s[512];      // G row i, natural order
    __shared__ float sc[512];       // inclusive prefix sums of sorted e
    __shared__ float wtot[4];
    __shared__ float red[4];
    __shared__ int   p_s;           // sorted position of i
    __shared__ int   lastg_s, lastf_s;

    const float* Grow = G + (size_t)i * n;

    // ---- staging (vectorized float2/int2: thread t covers 2t, 2t+1) ----
    {
        float2 mv = ((const float2*)mlab)[t];
        int2   pv = ((const int2*)perm)[t];
        float2 dv = ((const float2*)diag)[t];
        float2 gv = ((const float2*)Grow)[t];
        m_s[2 * t] = mv.x;  m_s[2 * t + 1] = mv.y;
        pm_s[2 * t] = pv.x; pm_s[2 * t + 1] = pv.y;
        dg_s[2 * t] = dv.x; dg_s[2 * t + 1] = dv.y;
        g_s[2 * t] = gv.x;  g_s[2 * t + 1] = gv.y;
    }
    const float li = labels[i];     // uniform scalar load
    const float di = diag[i];
    __syncthreads();

    // ---- per sorted position q in {2t, 2t+1}: logit, e, D ----
    float lgt[2], Dk[2], ev[2];
    int   jn[2];
    #pragma unroll
    for (int qq = 0; qq < 2; ++qq) {
        const int q = 2 * t + qq;
        const int j = pm_s[q];                   // natural index
        jn[qq] = j;
        float gq = g_s[j];                       // scattered LDS (2/thread)
        float sq = fmaxf(2.f - 2.f * gq * rsqrtf(di * dg_s[j]), 0.f);
        float lg = 0.5f * sqrtf(sq);
        lgt[qq] = lg;
        ev[qq]  = (j == i) ? 0.f : __expf(lg);
        Dk[qq]  = fabsf(m_s[q] - li);            // == fabsf(li - labels[j])
        if (j == i) p_s = q;
    }

    // ---- inclusive prefix scan of sorted e (register-seeded shfl scan) ----
    {
        float ps = ev[0] + ev[1];
        #pragma unroll
        for (int m = 1; m < 64; m <<= 1) {
            float v = __shfl_up(ps, m);
            if (lane >= m) ps += v;
        }
        if (lane == 63) wtot[w] = ps;
        __syncthreads();
        float woff = 0.f;
        #pragma unroll
        for (int w2 = 0; w2 < 4; ++w2) woff += (w2 < w) ? wtot[w2] : 0.f;
        float inc1 = woff + ps;          // inclusive through 2t+1
        sc[2 * t]     = inc1 - ev[1];    // inclusive through 2t
        sc[2 * t + 1] = inc1;
        __syncthreads();
    }
    const float tot = wtot[0] + wtot[1] + wtot[2] + wtot[3];
    const int p = p_s;

    // ---- per q: denom via two monotone binary searches (exact mask) ----
    float acc = 0.f;
    #pragma unroll
    for (int qq = 0; qq < 2; ++qq) {
        if (jn[qq] == i) continue;
        const float D = Dk[qq];
        int lo = 0, hi = p + 1;     // left half: dist non-increasing
        while (lo < hi) {
            int mid = (lo + hi) >> 1;
            if (fabsf(m_s[mid] - li) >= D) lo = mid + 1; else hi = mid;
        }
        const int cL = lo;                 // masked left = [0, cL)
        lo = p; hi = n;             // right half: dist non-decreasing
        while (lo < hi) {
            int mid = (lo + hi) >> 1;
            if (fabsf(m_s[mid] - li) >= D) hi = mid; else lo = mid + 1;
        }
        const int rI = lo;                 // masked right = [rI, n)
        float S = (cL > 0 ? sc[cL - 1] : 0.f) + tot - (rI > 0 ? sc[rI - 1] : 0.f);
        acc += lgt[qq] - __logf(S);
    }

    // ---- block reduce ----
    #pragma unroll
    for (int off = 32; off > 0; off >>= 1) acc += __shfl_down(acc, off);
    if (lane == 0) red[w] = acc;
    __syncthreads();

    // ---- two-tier spin-free finalize ----
    const int g = i >> 4;                       // group of 16 rows
    if (t == 0) {
        float rs = red[0] + red[1] + red[2] + red[3];
        __hip_atomic_store(&row_sums[i], rs, __ATOMIC_RELEASE,
                           __HIP_MEMORY_SCOPE_AGENT);
        unsigned prev = __hip_atomic_fetch_add(&ctrs[g * 64], 1u,
                                               __ATOMIC_ACQ_REL,
                                               __HIP_MEMORY_SCOPE_AGENT);
        lastg_s = (prev == 15u);                // 16-deep max serialization
    }
    __syncthreads();
    if (!lastg_s) return;

    // group's last arriver: tree-reduce its 16 row_sums (fixed order)
    if (w == 0) {
        float v = 0.f;
        if (lane < 16)
            v = __hip_atomic_load(&row_sums[g * 16 + lane], __ATOMIC_ACQUIRE,
                                  __HIP_MEMORY_SCOPE_AGENT);
        #pragma unroll
        for (int off = 8; off > 0; off >>= 1) v += __shfl_down(v, off);
        if (lane == 0) {
            __hip_atomic_store(&gsum[g], v, __ATOMIC_RELEASE,
                               __HIP_MEMORY_SCOPE_AGENT);
            unsigned prev = __hip_atomic_fetch_add(&ctrs[32 * 64], 1u,
                                                   __ATOMIC_ACQ_REL,
                                                   __HIP_MEMORY_SCOPE_AGENT);
            lastf_s = (prev == 31u);            // 32-deep max serialization
        }
    }
    __syncthreads();
    if (!lastf_s) return;

    // overall last arriver: tree-reduce the 32 group sums (fixed order)
    if (w == 0) {
        float v = 0.f;
        if (lane < 32)
            v = __hip_atomic_load(&gsum[lane], __ATOMIC_ACQUIRE,
                                  __HIP_MEMORY_SCOPE_AGENT);
        #pragma unroll
        for (int off = 16; off > 0; off >>= 1) v += __shfl_down(v, off);
        if (lane == 0)
            out[0] = -v / ((float)n * ((float)n - 1.0f));
    }
}

extern "C" void kernel_launch(void* const* d_in, const int* in_sizes, int n_in,
                              void* d_out, int out_size, void* d_ws, size_t ws_size,
                              hipStream_t stream) {
    const float* F      = (const float*)d_in[0];
    const float* labels = (const float*)d_in[1];
    int n = in_sizes[1];            // 512
    int d = in_sizes[0] / n;        // 512
    float* out = (float*)d_out;

    char* ws = (char*)d_ws;
    unsigned* ctrs    = (unsigned*)ws;                  // 33 x 256B-strided u32
    float* gsum       = (float*)(ws + 9216);            // 32 floats
    float* row_sums   = (float*)(ws + 10240);           // n floats
    float* diag       = (float*)(ws + 12288);           // n floats
    float* mlab       = (float*)(ws + 16384);           // n floats (sorted)
    int*   perm       = (int*)(ws + 18432);             // n ints
    float* G          = (float*)(ws + 20480);           // n*n fp32

    k_gemm_rank<<<258, 256, 0, stream>>>(F, labels, G, diag, mlab, perm,
                                         ctrs, n, d);
    k_loss<<<n, 256, 0, stream>>>(labels, G, diag, mlab, perm,
                                  row_sums, gsum, ctrs, out, n);
}

// Round 15
// 26.042 us; speedup vs baseline: 1.3960x; 1.3960x over previous
//
#include <hip/hip_runtime.h>
#include <hip/hip_bf16.h>
#include <math.h>

// ---------------------------------------------------------------------------
// RnCLoss: loss = -1/(n(n-1)) * sum_{i, k!=i} [ logit(i,k) - log denom(i,k) ]
//   logit(i,j) = 0.5*sqrt(max(2 - 2*G_ij*rsqrt(G_ii*G_jj), 0)), G = F F^T
//   denom(i,k) = sum_{j!=i, |l_i-l_j| >= |l_i-l_k|} exp(logit(i,j))
//
// R13 structure (best measured: 25.8 us). R14's in-kernel finalize regressed
// +10.5 us -> reverted. LEDGER RULE (R4/R6/R12/R14): on MI355X a stream
// dispatch boundary (~3.5 us) is strictly cheaper than ANY in-kernel
// agent-scope atomic/flag protocol (~10+ us each) — always prefer a third
// tiny kernel over an exit-time global handshake.
//
// Kernel 1 (258 blocks):
//   blocks 0..255 : 32x32-tile bf16-MFMA GEMM, SINGLE-SHOT K staging
//     (one coalesced burst, one __syncthreads, 16 ds_read_b128+MFMA steps,
//      XOR-swizzled 64KB LDS image).
//   blocks 256,257: brute-force stable label ranks -> mlab[], perm[].
// Kernel 2 (512 blocks): sorted-domain per-row loss; plain-store exit.
// Kernel 3 (1 block): fixed-order final reduction.
// ---------------------------------------------------------------------------

typedef __attribute__((ext_vector_type(8))) short          short8;
typedef __attribute__((ext_vector_type(4))) unsigned short ushort4v;
typedef __attribute__((ext_vector_type(4))) float          f32x4;

static __device__ __forceinline__ unsigned short bf16_bits(float f) {
    __hip_bfloat16 h = __float2bfloat16(f);  // RNE
    return *reinterpret_cast<unsigned short*>(&h);
}

// Kernel 1 -------------------------------------------------------------------
// Requires d == 512 (fixed by the problem's setup_inputs).
__global__ __launch_bounds__(256) void k_gemm_rank(const float* __restrict__ F,
                                                   const float* __restrict__ labels,
                                                   float* __restrict__ G,
                                                   float* __restrict__ diag,
                                                   float* __restrict__ mlab,
                                                   int* __restrict__ perm,
                                                   int n, int d) {
    // 64 KB LDS pool: A image [32][512] + B image [32][512] bf16 (XOR-swizzled)
    __shared__ unsigned short Asm[32][512];
    __shared__ unsigned short Bsm[32][512];

    const int b = blockIdx.x;
    const int t = threadIdx.x;

    if (b >= 256) {
        // ---- brute-force stable ranks (blocks 256,257); reuse LDS pool ----
        float* ls = (float*)&Asm[0][0];
        for (int x = t; x < n; x += 256) ls[x] = labels[x];
        __syncthreads();
        const int j = (b - 256) * 256 + t;
        const float lj = ls[j];
        int cnt = 0;
        #pragma unroll 8
        for (int x = 0; x < 512; ++x) {
            float lx = ls[x];                   // wave-uniform -> broadcast
            cnt += (lx < lj) || (lx == lj && x < j);
        }
        mlab[cnt] = lj;                          // ranks unique -> no race
        perm[cnt] = j;
        return;
    }

    // ---- GEMM: 32x32 tile, 4 waves (one 16x16 frag each), BK = 512 ----
    const int l  = t & 63;
    const int w  = t >> 6;
    const int wr = (w >> 1) << 4;   // frag row base: 0/16
    const int wc = (w & 1) << 4;    // frag col base: 0/16

    const int i0 = (b >> 4) << 5;
    const int j0 = (b & 15) << 5;

    const int fr = l & 15;          // frag row within 16x16
    const int fk = (l >> 4) << 3;   // frag k base: 0,8,16,24

    // ---- single-shot staging: 16 passes x (2 coalesced float4 loads) ----
    // pass p: linear idx = p*1024 + t*4  ->  row = idx>>9, col = idx&511
    // LDS col XOR-swizzled at 16B granule: cu = col ^ ((row&7)<<3)
    #pragma unroll
    for (int p = 0; p < 16; ++p) {
        const int idx = p * 1024 + t * 4;
        const int row = idx >> 9;
        const int col = idx & 511;
        float4 av = *(const float4*)&F[(size_t)(i0 + row) * 512 + col];
        float4 bv = *(const float4*)&F[(size_t)(j0 + row) * 512 + col];
        ushort4v ua, ub;
        ua[0] = bf16_bits(av.x); ua[1] = bf16_bits(av.y);
        ua[2] = bf16_bits(av.z); ua[3] = bf16_bits(av.w);
        ub[0] = bf16_bits(bv.x); ub[1] = bf16_bits(bv.y);
        ub[2] = bf16_bits(bv.z); ub[3] = bf16_bits(bv.w);
        const int cu = col ^ ((row & 7) << 3);
        *(ushort4v*)&Asm[row][cu] = ua;
        *(ushort4v*)&Bsm[row][cu] = ub;
    }
    __syncthreads();   // the only barrier

    // ---- 16 K-steps: 2 x ds_read_b128 + 1 MFMA each, no further syncs ----
    const int rA = wr + fr;
    const int rB = wc + fr;
    const int sxA = (rA & 7) << 3;
    const int sxB = (rB & 7) << 3;
    f32x4 acc = {};
    #pragma unroll
    for (int ks = 0; ks < 16; ++ks) {
        const int colk = ks * 32 + fk;
        short8 af = *(const short8*)&Asm[rA][colk ^ sxA];
        short8 bf = *(const short8*)&Bsm[rB][colk ^ sxB];
        acc = __builtin_amdgcn_mfma_f32_16x16x32_bf16(af, bf, acc, 0, 0, 0);
    }

    // ---- epilogue: C/D mapping col=lane&15, row=(lane>>4)*4+r (G symm.) ----
    const int orow = (l >> 4) << 2;
    #pragma unroll
    for (int r = 0; r < 4; ++r) {
        int gi = i0 + wr + orow + r;
        int gj = j0 + wc + fr;
        float v = acc[r];
        G[(size_t)gi * n + gj] = v;
        if (gi == gj) diag[gi] = v;
    }
}

// Kernel 2: sorted-domain per-row loss (proven R11-R13 body) ------------------
__global__ __launch_bounds__(256) void k_loss(const float* __restrict__ labels,
                                              const float* __restrict__ G,
                                              const float* __restrict__ diag,
                                              const float* __restrict__ mlab,
                                              const int* __restrict__ perm,
                                              float* __restrict__ row_sums,
                                              int n) {
    const int i    = blockIdx.x;
    const int t    = threadIdx.x;
    const int lane = t & 63;
    const int w    = t >> 6;

    __shared__ float m_s[512];      // sorted labels
    __shared__ int   pm_s[512];     // sorted pos -> natural index
    __shared__ float dg_s[512];     // diag, natural order
    __shared__ float g_s[512];      // G row i, natural order
    __shared__ float sc[512];       // inclusive prefix sums of sorted e
    __shared__ float wtot[4];
    __shared__ float red[4];
    __shared__ int   p_s;           // sorted position of i

    const float* Grow = G + (size_t)i * n;

    // ---- staging (vectorized float2/int2: thread t covers 2t, 2t+1) ----
    {
        float2 mv = ((const float2*)mlab)[t];
        int2   pv = ((const int2*)perm)[t];
        float2 dv = ((const float2*)diag)[t];
        float2 gv = ((const float2*)Grow)[t];
        m_s[2 * t] = mv.x;  m_s[2 * t + 1] = mv.y;
        pm_s[2 * t] = pv.x; pm_s[2 * t + 1] = pv.y;
        dg_s[2 * t] = dv.x; dg_s[2 * t + 1] = dv.y;
        g_s[2 * t] = gv.x;  g_s[2 * t + 1] = gv.y;
    }
    const float li = labels[i];     // uniform scalar load
    const float di = diag[i];
    __syncthreads();

    // ---- per sorted position q in {2t, 2t+1}: logit, e, D ----
    float lgt[2], Dk[2], ev[2];
    int   jn[2];
    #pragma unroll
    for (int qq = 0; qq < 2; ++qq) {
        const int q = 2 * t + qq;
        const int j = pm_s[q];                   // natural index
        jn[qq] = j;
        float gq = g_s[j];                       // scattered LDS (2/thread)
        float sq = fmaxf(2.f - 2.f * gq * rsqrtf(di * dg_s[j]), 0.f);
        float lg = 0.5f * sqrtf(sq);
        lgt[qq] = lg;
        ev[qq]  = (j == i) ? 0.f : __expf(lg);
        Dk[qq]  = fabsf(m_s[q] - li);            // == fabsf(li - labels[j])
        if (j == i) p_s = q;
    }

    // ---- inclusive prefix scan of sorted e (register-seeded shfl scan) ----
    {
        float ps = ev[0] + ev[1];
        #pragma unroll
        for (int m = 1; m < 64; m <<= 1) {
            float v = __shfl_up(ps, m);
            if (lane >= m) ps += v;
        }
        if (lane == 63) wtot[w] = ps;
        __syncthreads();
        float woff = 0.f;
        #pragma unroll
        for (int w2 = 0; w2 < 4; ++w2) woff += (w2 < w) ? wtot[w2] : 0.f;
        float inc1 = woff + ps;          // inclusive through 2t+1
        sc[2 * t]     = inc1 - ev[1];    // inclusive through 2t
        sc[2 * t + 1] = inc1;
        __syncthreads();
    }
    const float tot = wtot[0] + wtot[1] + wtot[2] + wtot[3];
    const int p = p_s;

    // ---- per q: denom via two monotone binary searches (exact mask).
    //      Lanes hold CONSECUTIVE q -> monotone keys -> broadcast-mostly mids.
    float acc = 0.f;
    #pragma unroll
    for (int qq = 0; qq < 2; ++qq) {
        if (jn[qq] == i) continue;
        const float D = Dk[qq];
        // left half [0, p]: dist non-increasing; cL = first idx with dist < D
        int lo = 0, hi = p + 1;
        while (lo < hi) {
            int mid = (lo + hi) >> 1;
            if (fabsf(m_s[mid] - li) >= D) lo = mid + 1; else hi = mid;
        }
        const int cL = lo;                 // masked left = [0, cL)
        // right half [p, n): dist non-decreasing; rI = first idx with dist >= D
        lo = p; hi = n;
        while (lo < hi) {
            int mid = (lo + hi) >> 1;
            if (fabsf(m_s[mid] - li) >= D) hi = mid; else lo = mid + 1;
        }
        const int rI = lo;                 // masked right = [rI, n)
        // overlap can only be position p where e = 0 -> harmless
        float S = (cL > 0 ? sc[cL - 1] : 0.f) + tot - (rI > 0 ? sc[rI - 1] : 0.f);
        acc += lgt[qq] - __logf(S);
    }

    // ---- block reduce; plain-store exit (no atomics, no RMW tail) ----
    #pragma unroll
    for (int off = 32; off > 0; off >>= 1) acc += __shfl_down(acc, off);
    if (lane == 0) red[w] = acc;
    __syncthreads();
    if (t == 0) row_sums[i] = red[0] + red[1] + red[2] + red[3];
}

// Kernel 3: fixed-order final reduction (1 block) -----------------------------
__global__ __launch_bounds__(256) void k_final(const float* __restrict__ row_sums,
                                               float* __restrict__ out, int n) {
    const int t = threadIdx.x;
    __shared__ float red[4];
    float s = 0.f;
    for (int r = t; r < n; r += 256) s += row_sums[r];
    #pragma unroll
    for (int off = 32; off > 0; off >>= 1) s += __shfl_down(s, off);
    const int lane = t & 63, w = t >> 6;
    if (lane == 0) red[w] = s;
    __syncthreads();
    if (t == 0) {
        float tot = red[0] + red[1] + red[2] + red[3];
        out[0] = -tot / ((float)n * ((float)n - 1.0f));
    }
}

extern "C" void kernel_launch(void* const* d_in, const int* in_sizes, int n_in,
                              void* d_out, int out_size, void* d_ws, size_t ws_size,
                              hipStream_t stream) {
    const float* F      = (const float*)d_in[0];
    const float* labels = (const float*)d_in[1];
    int n = in_sizes[1];            // 512
    int d = in_sizes[0] / n;        // 512
    float* out = (float*)d_out;

    char* ws = (char*)d_ws;
    float* row_sums   = (float*)(ws + 4096);            // n floats
    float* diag       = (float*)(ws + 8192);            // n floats
    float* mlab       = (float*)(ws + 12288);           // n floats (sorted)
    int*   perm       = (int*)(ws + 14336);             // n ints
    float* G          = (float*)(ws + 16384);           // n*n fp32

    k_gemm_rank<<<258, 256, 0, stream>>>(F, labels, G, diag, mlab, perm, n, d);
    k_loss<<<n, 256, 0, stream>>>(labels, G, diag, mlab, perm, row_sums, n);
    k_final<<<1, 256, 0, stream>>>(row_sums, out, n);
}